// Round 1
// baseline (576.325 us; speedup 1.0000x reference)
//
#include <hip/hip_runtime.h>
#include <cstddef>

#define BB 16
#define TT 256
#define OBSD 128
#define W0D 256
#define HID 256
#define CTX 64
#define NA 64
#define HNH 128
#define HNOUT 1344
#define MROWS 4096  // B*T

__device__ __forceinline__ float sigm(float x) { return 1.f / (1.f + __expf(-x)); }
__device__ __forceinline__ float tanh_f(float x) { return 1.f - 2.f / (__expf(2.f * x) + 1.f); }

// ---------------------------------------------------------------------------
// Generic fp32 GEMM: C[M,N] = act(A[M,K] @ Bw[N,K]^T + bias[N]) * scale
// Tiles: 128x64, BK=16, thread-tile 8x4, 256 threads.
// Requires: M % 128 == 0, N % 64 == 0, K % 16 == 0 (true for all calls here).
// ---------------------------------------------------------------------------
__global__ __launch_bounds__(256) void gemm_bt(
    const float* __restrict__ A, const float* __restrict__ Bw,
    const float* __restrict__ bias, float* __restrict__ C,
    int M, int N, int K, int act, float scale)
{
    __shared__ float As[16][132];  // row stride 132 floats = 528B (16B multiple)
    __shared__ float Bs[16][68];   // 272B row stride (16B multiple)
    const int tid = threadIdx.x;
    const int m0 = blockIdx.x * 128, n0 = blockIdx.y * 64;
    const int tx = tid & 15, ty = tid >> 4;
    float acc[8][4] = {};
    for (int k0 = 0; k0 < K; k0 += 16) {
#pragma unroll
        for (int l = 0; l < 2; ++l) {
            int v = tid + l * 256;           // 0..511 float4 slots (128 rows x 4)
            int row = v >> 2, kc = (v & 3) << 2;
            float4 a4 = *(const float4*)(A + (size_t)(m0 + row) * K + k0 + kc);
            As[kc + 0][row] = a4.x; As[kc + 1][row] = a4.y;
            As[kc + 2][row] = a4.z; As[kc + 3][row] = a4.w;
        }
        {
            int row = tid >> 2, kc = (tid & 3) << 2;  // 64 rows x 4 float4
            float4 b4 = *(const float4*)(Bw + (size_t)(n0 + row) * K + k0 + kc);
            Bs[kc + 0][row] = b4.x; Bs[kc + 1][row] = b4.y;
            Bs[kc + 2][row] = b4.z; Bs[kc + 3][row] = b4.w;
        }
        __syncthreads();
#pragma unroll
        for (int k = 0; k < 16; ++k) {
            float4 a0 = *(const float4*)&As[k][ty * 8];
            float4 a1 = *(const float4*)&As[k][ty * 8 + 4];
            float4 b0 = *(const float4*)&Bs[k][tx * 4];
            float a[8] = {a0.x, a0.y, a0.z, a0.w, a1.x, a1.y, a1.z, a1.w};
            float b[4] = {b0.x, b0.y, b0.z, b0.w};
#pragma unroll
            for (int i = 0; i < 8; ++i)
#pragma unroll
                for (int jj = 0; jj < 4; ++jj)
                    acc[i][jj] = fmaf(a[i], b[jj], acc[i][jj]);
        }
        __syncthreads();
    }
    const float4 bia = *(const float4*)(bias + n0 + tx * 4);
    const float bb[4] = {bia.x, bia.y, bia.z, bia.w};
#pragma unroll
    for (int i = 0; i < 8; ++i) {
        int m = m0 + ty * 8 + i;
        float4 o;
        float* op = &o.x;
#pragma unroll
        for (int jj = 0; jj < 4; ++jj) {
            float v = acc[i][jj] + bb[jj];
            if (act) v = fmaxf(v, 0.f);
            op[jj] = v * scale;
        }
        *(float4*)(C + (size_t)m * N + n0 + tx * 4) = o;
    }
}

// ---------------------------------------------------------------------------
// GRU scan. 16 blocks (one per batch, independent recurrences -> no inter-WG
// sync), 512 threads: thread (j = tid&255, ks = tid>>8) owns rows {j, j+256,
// j+512} of Whh over K-half ks, cached in VGPRs as packed f16 (192 VGPRs).
// h kept in LDS as f16 (broadcast reads); partial dots reduced across the two
// K-halves through LDS. xg precomputed (GEMM) so per step only the 768x256
// recurrent matvec + gate math remains.
// ---------------------------------------------------------------------------
typedef _Float16 h2v __attribute__((ext_vector_type(2)));

#if defined(__has_builtin)
#if __has_builtin(__builtin_amdgcn_fdot2)
#define HAVE_FDOT2 1
#endif
#endif

__device__ __forceinline__ float dot2acc(h2v a, h2v b, float c) {
#ifdef HAVE_FDOT2
    return __builtin_amdgcn_fdot2(a, b, c, false);
#else
    return c + (float)a[0] * (float)b[0] + (float)a[1] * (float)b[1];
#endif
}

__global__ __launch_bounds__(512, 2) void gru_kernel(
    const float* __restrict__ XG, const float* __restrict__ Whh,
    const float* __restrict__ bhh, const float* __restrict__ h0,
    float* __restrict__ FE, float* __restrict__ HT)
{
    __shared__ __align__(16) _Float16 hbuf[HID];
    __shared__ float part[3][HID];
    const int b = blockIdx.x;
    const int tid = threadIdx.x;
    const int j = tid & 255, ks = tid >> 8;
    h2v w[3][64];
#pragma unroll
    for (int r = 0; r < 3; ++r) {
        const float* wr = Whh + (size_t)(r * HID + j) * HID + ks * 128;
#pragma unroll
        for (int i = 0; i < 64; ++i) {
            float2 f = *(const float2*)(wr + 2 * i);
            h2v t; t[0] = (_Float16)f.x; t[1] = (_Float16)f.y;
            w[r][i] = t;
        }
    }
    const float br = bhh[j], bz = bhh[HID + j], bn = bhh[2 * HID + j];
    float hj = 0.f;
    if (ks == 0) {
        hj = h0[b * HID + j];
        hbuf[j] = (_Float16)hj;
    }
    __syncthreads();
    const float* xg = XG + (size_t)b * TT * 768;
    for (int t = 0; t < TT; ++t) {
        float xr = 0.f, xz = 0.f, xn = 0.f;
        if (ks == 0) {
            const float* p = xg + (size_t)t * 768 + j;
            xr = p[0]; xz = p[256]; xn = p[512];
        }
        float pr = 0.f, pz = 0.f, pn = 0.f;
        const h2v* hp = (const h2v*)hbuf + ks * 64;
#pragma unroll
        for (int i = 0; i < 64; ++i) {
            h2v hh = hp[i];
            pr = dot2acc(w[0][i], hh, pr);
            pz = dot2acc(w[1][i], hh, pz);
            pn = dot2acc(w[2][i], hh, pn);
        }
        if (ks) { part[0][j] = pr; part[1][j] = pz; part[2][j] = pn; }
        __syncthreads();
        if (ks == 0) {
            float hr = pr + part[0][j] + br;
            float hz = pz + part[1][j] + bz;
            float hn = pn + part[2][j] + bn;
            float r = sigm(xr + hr);
            float z = sigm(xz + hz);
            float n = tanh_f(xn + r * hn);
            hj = (1.f - z) * n + z * hj;
            hbuf[j] = (_Float16)hj;
            FE[((size_t)b * TT + t) * HID + j] = hj;
        }
        __syncthreads();
    }
    if (ks == 0) HT[b * HID + j] = hj;
}

// ---------------------------------------------------------------------------
// Head part 1 per 16-row tile: ctx_mu, ctx_lv(+clip), gate, h1, h2.
// Activations staged LDS-transposed [k][t] so the 8-wide t-vector is
// contiguous (2x float4 per k).
// ---------------------------------------------------------------------------
__global__ __launch_bounds__(256) void mid_kernel(
    const float* __restrict__ FE,
    const float* __restrict__ W_mu, const float* __restrict__ b_mu,
    const float* __restrict__ W_lv, const float* __restrict__ b_lv,
    const float* __restrict__ gw_p, const float* __restrict__ gb_p,
    const float* __restrict__ W1, const float* __restrict__ b1,
    const float* __restrict__ W2, const float* __restrict__ b2,
    float* __restrict__ GATE, float* __restrict__ H2out)
{
    __shared__ float fT[256][20];   // row stride 80B (16B multiple)
    __shared__ float muT[64][20];
    __shared__ float h1T[128][20];
    __shared__ float lvb[16][68];
    const int tid = threadIdx.x;
    const int r0 = blockIdx.x * 16;
#pragma unroll
    for (int l = 0; l < 4; ++l) {
        int v = tid + l * 256;
        int t = v >> 6, kc = (v & 63) << 2;
        float4 f = *(const float4*)(FE + (size_t)(r0 + t) * HID + kc);
        fT[kc + 0][t] = f.x; fT[kc + 1][t] = f.y;
        fT[kc + 2][t] = f.z; fT[kc + 3][t] = f.w;
    }
    __syncthreads();
    const int c = tid & 127, tg = tid >> 7;
    // Phase A: mu (c<64) / clipped lv (c>=64), 8 t's per thread
    {
        const float* wrow = (c < 64) ? (W_mu + (size_t)c * HID)
                                     : (W_lv + (size_t)(c - 64) * HID);
        float acc[8] = {};
        for (int k = 0; k < 256; k += 4) {
            float4 wv = *(const float4*)(wrow + k);
#pragma unroll
            for (int e = 0; e < 4; ++e) {
                float wsc = (&wv.x)[e];
                float4 fa = *(const float4*)&fT[k + e][tg * 8];
                float4 fb = *(const float4*)&fT[k + e][tg * 8 + 4];
                acc[0] = fmaf(wsc, fa.x, acc[0]); acc[1] = fmaf(wsc, fa.y, acc[1]);
                acc[2] = fmaf(wsc, fa.z, acc[2]); acc[3] = fmaf(wsc, fa.w, acc[3]);
                acc[4] = fmaf(wsc, fb.x, acc[4]); acc[5] = fmaf(wsc, fb.y, acc[5]);
                acc[6] = fmaf(wsc, fb.z, acc[6]); acc[7] = fmaf(wsc, fb.w, acc[7]);
            }
        }
        float bb2 = (c < 64) ? b_mu[c] : b_lv[c - 64];
#pragma unroll
        for (int i2 = 0; i2 < 8; ++i2) {
            int t = tg * 8 + i2;
            float v = acc[i2] + bb2;
            if (c < 64) muT[c][t] = v;
            else        lvb[t][c - 64] = fminf(fmaxf(v, -6.f), 4.f);
        }
    }
    __syncthreads();
    // gate (reads lvb) runs alongside phase B (reads muT) — disjoint data
    if (tid < 16) {
        float s = 0.f;
        for (int i2 = 0; i2 < 64; ++i2) s += lvb[tid][i2];
        float mean = s * (1.f / 64.f);
        GATE[r0 + tid] = sigm(gw_p[0] * (-mean) + gb_p[0]);
    }
    // Phase B: h1 = relu(mu @ W1^T + b1)
    {
        const float* wrow = W1 + (size_t)c * CTX;
        float acc[8] = {};
        for (int k = 0; k < 64; k += 4) {
            float4 wv = *(const float4*)(wrow + k);
#pragma unroll
            for (int e = 0; e < 4; ++e) {
                float wsc = (&wv.x)[e];
                float4 fa = *(const float4*)&muT[k + e][tg * 8];
                float4 fb = *(const float4*)&muT[k + e][tg * 8 + 4];
                acc[0] = fmaf(wsc, fa.x, acc[0]); acc[1] = fmaf(wsc, fa.y, acc[1]);
                acc[2] = fmaf(wsc, fa.z, acc[2]); acc[3] = fmaf(wsc, fa.w, acc[3]);
                acc[4] = fmaf(wsc, fb.x, acc[4]); acc[5] = fmaf(wsc, fb.y, acc[5]);
                acc[6] = fmaf(wsc, fb.z, acc[6]); acc[7] = fmaf(wsc, fb.w, acc[7]);
            }
        }
        float bb2 = b1[c];
#pragma unroll
        for (int i2 = 0; i2 < 8; ++i2) {
            int t = tg * 8 + i2;
            h1T[c][t] = fmaxf(acc[i2] + bb2, 0.f);
        }
    }
    __syncthreads();
    // Phase C: h2 = relu(h1 @ W2^T + b2) -> global
    {
        const float* wrow = W2 + (size_t)c * HNH;
        float acc[8] = {};
        for (int k = 0; k < 128; k += 4) {
            float4 wv = *(const float4*)(wrow + k);
#pragma unroll
            for (int e = 0; e < 4; ++e) {
                float wsc = (&wv.x)[e];
                float4 fa = *(const float4*)&h1T[k + e][tg * 8];
                float4 fb = *(const float4*)&h1T[k + e][tg * 8 + 4];
                acc[0] = fmaf(wsc, fa.x, acc[0]); acc[1] = fmaf(wsc, fa.y, acc[1]);
                acc[2] = fmaf(wsc, fa.z, acc[2]); acc[3] = fmaf(wsc, fa.w, acc[3]);
                acc[4] = fmaf(wsc, fb.x, acc[4]); acc[5] = fmaf(wsc, fb.y, acc[5]);
                acc[6] = fmaf(wsc, fb.z, acc[6]); acc[7] = fmaf(wsc, fb.w, acc[7]);
            }
        }
        float bb2 = b2[c];
#pragma unroll
        for (int i2 = 0; i2 < 8; ++i2) {
            int t = tg * 8 + i2;
            H2out[(size_t)(r0 + t) * HNH + c] = fmaxf(acc[i2] + bb2, 0.f);
        }
    }
}

// ---------------------------------------------------------------------------
// Final: low-rank contraction s_r = feats·wf[:,r] (shuffle-reduced), then
// logits = feats@W_pol^T + b_pol + gate*(s@af + db). Never materializes
// delta_w [256,64].
// ---------------------------------------------------------------------------
__global__ __launch_bounds__(256) void final_kernel(
    const float* __restrict__ FE, const float* __restrict__ DL,
    const float* __restrict__ GATE, const float* __restrict__ W_pol,
    const float* __restrict__ b_pol, float* __restrict__ OUT)
{
    __shared__ float fs[4][256];
    __shared__ float dsb[4][HNOUT];
    __shared__ float sr[4][4];
    __shared__ float gg[4];
    const int tid = threadIdx.x;
    const int r0 = blockIdx.x * 4;
    {
        int t = tid >> 6, kc = (tid & 63) << 2;
        *(float4*)&fs[t][kc] = *(const float4*)(FE + (size_t)(r0 + t) * HID + kc);
    }
    for (int v = tid; v < 1344; v += 256) {  // 1344 float4 slots (4 rows x 336)
        int t = v / 336, q = v - t * 336;
        ((float4*)&dsb[t][0])[q] = ((const float4*)(DL + (size_t)(r0 + t) * HNOUT))[q];
    }
    if (tid < 4) gg[tid] = GATE[r0 + tid];
    __syncthreads();
    {
        const int t = tid >> 6, lane = tid & 63;
        float p0 = 0, p1 = 0, p2 = 0, p3 = 0;
#pragma unroll
        for (int hh = 0; hh < 4; ++hh) {
            int h = lane + hh * 64;
            float f = fs[t][h];
            float4 d4 = *(const float4*)&dsb[t][4 * h];  // wf[h, 0..3]
            p0 = fmaf(f, d4.x, p0); p1 = fmaf(f, d4.y, p1);
            p2 = fmaf(f, d4.z, p2); p3 = fmaf(f, d4.w, p3);
        }
#pragma unroll
        for (int off = 32; off >= 1; off >>= 1) {
            p0 += __shfl_down(p0, off);
            p1 += __shfl_down(p1, off);
            p2 += __shfl_down(p2, off);
            p3 += __shfl_down(p3, off);
        }
        if (lane == 0) { sr[t][0] = p0; sr[t][1] = p1; sr[t][2] = p2; sr[t][3] = p3; }
    }
    __syncthreads();
    {
        const int t = tid >> 6, a = tid & 63;
        const float* wrow = W_pol + (size_t)a * HID;
        float acc = 0.f;
        for (int k = 0; k < 256; k += 4) {
            float4 wv = *(const float4*)(wrow + k);
            float4 fv = *(const float4*)&fs[t][k];
            acc = fmaf(wv.x, fv.x, acc); acc = fmaf(wv.y, fv.y, acc);
            acc = fmaf(wv.z, fv.z, acc); acc = fmaf(wv.w, fv.w, acc);
        }
        float la = sr[t][0] * dsb[t][1024 + a] + sr[t][1] * dsb[t][1088 + a]
                 + sr[t][2] * dsb[t][1152 + a] + sr[t][3] * dsb[t][1216 + a]
                 + dsb[t][1280 + a];  // + db
        OUT[(size_t)(r0 + t) * NA + a] = acc + b_pol[a] + gg[t] * la;
    }
}

extern "C" void kernel_launch(void* const* d_in, const int* in_sizes, int n_in,
                              void* d_out, int out_size, void* d_ws, size_t ws_size,
                              hipStream_t stream) {
    const float* obs   = (const float*)d_in[0];
    const float* h0    = (const float*)d_in[1];
    const float* W_in  = (const float*)d_in[2];
    const float* b_in  = (const float*)d_in[3];
    const float* W_h1  = (const float*)d_in[4];
    const float* b_h1  = (const float*)d_in[5];
    const float* Wih   = (const float*)d_in[6];
    const float* Whh   = (const float*)d_in[7];
    const float* bih   = (const float*)d_in[8];
    const float* bhh   = (const float*)d_in[9];
    const float* W_mu  = (const float*)d_in[10];
    const float* b_mu  = (const float*)d_in[11];
    const float* W_lv  = (const float*)d_in[12];
    const float* b_lv  = (const float*)d_in[13];
    const float* gate_w= (const float*)d_in[14];
    const float* gate_b= (const float*)d_in[15];
    const float* W_pol = (const float*)d_in[16];
    const float* b_pol = (const float*)d_in[17];
    const float* hn_W1 = (const float*)d_in[18];
    const float* hn_b1 = (const float*)d_in[19];
    const float* hn_W2 = (const float*)d_in[20];
    const float* hn_b2 = (const float*)d_in[21];
    const float* hn_W3 = (const float*)d_in[22];
    const float* hn_b3 = (const float*)d_in[23];

    float* ws = (float*)d_ws;
    float* X1 = ws;                       // 4096*256   = 1,048,576
    float* X2 = X1 + 1048576;             // 4096*256
    float* XG = X2 + 1048576;             // 4096*768   = 3,145,728
    float* FE = XG + 3145728;             // 4096*256
    float* GA = FE + 1048576;             // 4096
    float* H2 = GA + 4096;                // 4096*128   = 524,288
    float* DL = H2 + 524288;              // 4096*1344  = 5,505,024
    (void)ws_size; (void)n_in; (void)in_sizes; (void)out_size;

    float* logits = (float*)d_out;
    float* hn_out = logits + (size_t)BB * TT * NA;  // 262144

    // x1 = relu(obs @ W_in^T + b_in)
    gemm_bt<<<dim3(32, 4), 256, 0, stream>>>(obs, W_in, b_in, X1, MROWS, 256, 128, 1, 1.f);
    // x2 = relu(x1 @ W_h1^T + b_h1)
    gemm_bt<<<dim3(32, 4), 256, 0, stream>>>(X1, W_h1, b_h1, X2, MROWS, 256, 256, 1, 1.f);
    // xg = x2 @ Wih^T + bih
    gemm_bt<<<dim3(32, 12), 256, 0, stream>>>(X2, Wih, bih, XG, MROWS, 768, 256, 0, 1.f);
    // sequential GRU scan -> feats, hT
    gru_kernel<<<16, 512, 0, stream>>>(XG, Whh, bhh, h0, FE, hn_out);
    // mu/lv/gate/h1/h2
    mid_kernel<<<256, 256, 0, stream>>>(FE, W_mu, b_mu, W_lv, b_lv, gate_w, gate_b,
                                        hn_W1, hn_b1, hn_W2, hn_b2, GA, H2);
    // deltas = (h2 @ hn_W3^T + hn_b3) * 0.05
    gemm_bt<<<dim3(32, 21), 256, 0, stream>>>(H2, hn_W3, hn_b3, DL, MROWS, HNOUT, 128, 0, 0.05f);
    // logits
    final_kernel<<<1024, 256, 0, stream>>>(FE, DL, GA, W_pol, b_pol, logits);
}